// Round 3
// baseline (680.593 us; speedup 1.0000x reference)
//
#include <hip/hip_runtime.h>
#include <hip/hip_bf16.h>
#include <math.h>

#define NB 4
#define NH 8
#define SLQ 2048
#define SLK 2048
#define DD 64
#define SK 40
#define NTOP 40
#define SCL 0.125f
#define CH 128
#define NCH (SLK / CH) /* 16 */
#define UB 4            /* top-queries per k_attn block */

typedef unsigned short ushort_t;

__device__ __forceinline__ float bf2f(unsigned int u16) {
    union { unsigned int i; float f; } v;
    v.i = u16 << 16;
    return v.f;
}
__device__ __forceinline__ ushort_t f2bf(float f) {
    union { float f; unsigned int i; } v;
    v.f = f;
    unsigned int x = v.i;
    unsigned int r = (x + 0x7FFFu + ((x >> 16) & 1u)) >> 16;  // RNE
    return (ushort_t)r;
}
// element load/store honoring runtime dtype flag (1 = fp32, 0 = bf16)
__device__ __forceinline__ float le(const void* p, size_t i, int f32) {
    return f32 ? ((const float*)p)[i] : bf2f(((const ushort_t*)p)[i]);
}
__device__ __forceinline__ void se(void* p, size_t i, int f32, float v) {
    if (f32) ((float*)p)[i] = v;
    else ((ushort_t*)p)[i] = f2bf(v);
}

// -------------------------------------------------- K0: dtype probe
// Under the bf16 interpretation, real bf16 normal data has ~100% sane
// exponents; fp32 data reinterpreted as bf16 halves has ~60% (low halves
// are exponent-random). flag = 1 means fp32.
__global__ void k_probe(const unsigned int* __restrict__ qw, int* __restrict__ flag)
{
    int t = threadIdx.x;  // 64 threads
    unsigned int w = qw[t * 37];
    int cnt = 0;
#pragma unroll
    for (int s = 0; s < 2; s++) {
        unsigned int h = (s == 0) ? (w & 0xffffu) : (w >> 16);
        unsigned int e = (h >> 7) & 0xffu;
        int ok = (e == 0) ? ((h & 0x7fu) == 0) : (e >= 100 && e <= 153);
        cnt += ok;
    }
#pragma unroll
    for (int off = 32; off > 0; off >>= 1) cnt += __shfl_xor(cnt, off);
    if (t == 0) flag[0] = (cnt >= 104) ? 0 : 1;
}

// -------------------------------------------------- K1: sampled M scores
__global__ __launch_bounds__(256) void k_sampleM(
    const void* __restrict__ q, const void* __restrict__ k,
    const int* __restrict__ isamp, const int* __restrict__ flag,
    float* __restrict__ M)
{
    int f32 = flag[0];
    int t = blockIdx.x * 256 + threadIdx.x;  // t = (b*NH+h)*SLQ + l
    int l  = t & (SLQ - 1);
    int bh = t >> 11;
    int h  = bh & (NH - 1);
    int b  = bh >> 3;

    size_t qoff = (((size_t)(b * SLQ + l)) * NH + h) * DD;
    float qr[DD];
    if (f32) {
        const float4* qp = (const float4*)((const float*)q + qoff);
#pragma unroll
        for (int i = 0; i < 16; i++) {
            float4 u = qp[i];
            qr[4 * i + 0] = u.x; qr[4 * i + 1] = u.y;
            qr[4 * i + 2] = u.z; qr[4 * i + 3] = u.w;
        }
    } else {
        const uint4* qp = (const uint4*)((const ushort_t*)q + qoff);
#pragma unroll
        for (int i = 0; i < 8; i++) {
            uint4 u = qp[i];
            unsigned int w[4] = {u.x, u.y, u.z, u.w};
#pragma unroll
            for (int j = 0; j < 4; j++) {
                qr[i * 8 + j * 2 + 0] = bf2f(w[j] & 0xffffu);
                qr[i * 8 + j * 2 + 1] = bf2f(w[j] >> 16);
            }
        }
    }

    float mx = -INFINITY, sm = 0.f;
    const int* ip = isamp + l * SK;
    for (int s = 0; s < SK; s++) {
        int ks = ip[s] & (SLK - 1);
        size_t koff = (((size_t)(b * SLK + ks)) * NH + h) * DD;
        float dot = 0.f;
        if (f32) {
            const float4* kp = (const float4*)((const float*)k + koff);
#pragma unroll
            for (int i = 0; i < 16; i++) {
                float4 u = kp[i];
                dot += qr[4 * i + 0] * u.x + qr[4 * i + 1] * u.y +
                       qr[4 * i + 2] * u.z + qr[4 * i + 3] * u.w;
            }
        } else {
            const uint4* kp = (const uint4*)((const ushort_t*)k + koff);
#pragma unroll
            for (int i = 0; i < 8; i++) {
                uint4 u = kp[i];
                unsigned int w[4] = {u.x, u.y, u.z, u.w};
#pragma unroll
                for (int j = 0; j < 4; j++) {
                    dot += qr[i * 8 + j * 2 + 0] * bf2f(w[j] & 0xffffu);
                    dot += qr[i * 8 + j * 2 + 1] * bf2f(w[j] >> 16);
                }
            }
        }
        mx = fmaxf(mx, dot);
        sm += dot;
    }
    M[t] = mx - sm * (1.0f / SK);
}

// -------------------------------------------------- K2: top-40 (NaN-proof)
__global__ __launch_bounds__(256) void k_topk(
    const float* __restrict__ M, int* __restrict__ topidx)
{
    int bh = blockIdx.x;
    int t = threadIdx.x;
    int lane = t & 63, wid = t >> 6;
    __shared__ float vals[SLQ];
    __shared__ float wbv[4];
    __shared__ int   wbi[4];
    const float* Mp = M + (size_t)bh * SLQ;
    for (int i = t; i < SLQ; i += 256) vals[i] = Mp[i];
    __syncthreads();
    for (int u = 0; u < NTOP; u++) {
        float bv = -INFINITY; int bi = t;  // in-range even if all NaN
        for (int i = t; i < SLQ; i += 256) {
            float v = vals[i];
            if (v > bv) { bv = v; bi = i; }  // ascending scan keeps lowest i on tie
        }
#pragma unroll
        for (int off = 32; off > 0; off >>= 1) {
            float ov = __shfl_xor(bv, off);
            int   oi = __shfl_xor(bi, off);
            if (ov > bv || (ov == bv && oi < bi)) { bv = ov; bi = oi; }
        }
        if (lane == 0) { wbv[wid] = bv; wbi[wid] = bi; }
        __syncthreads();
        if (t == 0) {
            float fv = wbv[0]; int fi = wbi[0];
#pragma unroll
            for (int w = 1; w < 4; w++) {
                if (wbv[w] > fv || (wbv[w] == fv && wbi[w] < fi)) { fv = wbv[w]; fi = wbi[w]; }
            }
            fi &= (SLQ - 1);  // clamp: garbage can't escape
            topidx[bh * NTOP + u] = fi;
            vals[fi] = -INFINITY;
        }
        __syncthreads();
    }
}

// -------------------------------------------------- K3: cumsum -> out (ALL rows)
__global__ __launch_bounds__(256) void k_scan(
    const void* __restrict__ v, const int* __restrict__ flag,
    void* __restrict__ out)
{
    int f32 = flag[0];
    int gid = blockIdx.x;
    int ch = gid & (NCH - 1);
    int bh = gid >> 4;
    int h = bh & 7, b = bh >> 3;
    int t = threadIdx.x;
    int d = t & 63, g = t >> 6;

    // phase A: partial sums of all rows before this chunk
    float ps = 0.f;
    int nprior = ch * CH;
    for (int r = g; r < nprior; r += 4)
        ps += le(v, (((size_t)(b * SLK + r)) * NH + h) * DD + d, f32);

    // phase B: sequential prefix within this thread's 32-row quarter
    float pre[32];
    float run = 0.f;
    int base_row = ch * CH + g * 32;
#pragma unroll 4
    for (int i = 0; i < 32; i++) {
        run += le(v, (((size_t)(b * SLK + base_row + i)) * NH + h) * DD + d, f32);
        pre[i] = run;
    }

    __shared__ float pgsum[4][DD];
    __shared__ float qsum[4][DD];
    pgsum[g][d] = ps;
    qsum[g][d] = run;
    __syncthreads();

    float base = pgsum[0][d] + pgsum[1][d] + pgsum[2][d] + pgsum[3][d];
    for (int qq = 0; qq < g; qq++) base += qsum[qq][d];

#pragma unroll 4
    for (int i = 0; i < 32; i++) {
        se(out, (((size_t)(b * SLQ + base_row + i)) * NH + h) * DD + d, f32, base + pre[i]);
    }
}

// -------------------------------------------------- K4: attention rows -> out
// block = (bh, ub): UB=4 top-queries. Runs AFTER k_scan; overwrites its rows.
__global__ __launch_bounds__(256) void k_attn(
    const void* __restrict__ q, const void* __restrict__ k,
    const void* __restrict__ v, const int* __restrict__ topidx,
    const int* __restrict__ flag, void* __restrict__ out)
{
    int f32 = flag[0];
    int gid = blockIdx.x;            // bh*(NTOP/UB) + ub
    int ub = gid % (NTOP / UB);
    int bh = gid / (NTOP / UB);
    int h  = bh & 7, b = bh >> 3;
    int t  = threadIdx.x;
    int lane = t & 63, wid = t >> 6;

    __shared__ float qr[UB][DD];
    __shared__ float sc[UB][SLK];      // 32 KB
    __shared__ float part[4 * UB][DD]; // 4 KB
    __shared__ float dinv[UB];
    __shared__ int   lqs[UB];

    if (t < UB) lqs[t] = topidx[bh * NTOP + ub * UB + t] & (SLQ - 1);
    __syncthreads();
    {
        int j = t >> 6, d = t & 63;
        qr[j][d] = le(q, (((size_t)(b * SLQ + lqs[j])) * NH + h) * DD + d, f32);
    }
    __syncthreads();

    // QK^T: thread kk handles one K row, dots against all UB queries
    for (int kk = t; kk < SLK; kk += 256) {
        float kr[DD];
        size_t koff = (((size_t)(b * SLK + kk)) * NH + h) * DD;
        if (f32) {
            const float4* kp = (const float4*)((const float*)k + koff);
#pragma unroll
            for (int i = 0; i < 16; i++) {
                float4 u = kp[i];
                kr[4 * i + 0] = u.x; kr[4 * i + 1] = u.y;
                kr[4 * i + 2] = u.z; kr[4 * i + 3] = u.w;
            }
        } else {
            const uint4* kp = (const uint4*)((const ushort_t*)k + koff);
#pragma unroll
            for (int i = 0; i < 8; i++) {
                uint4 uu = kp[i];
                unsigned int w[4] = {uu.x, uu.y, uu.z, uu.w};
#pragma unroll
                for (int j = 0; j < 4; j++) {
                    kr[i * 8 + j * 2 + 0] = bf2f(w[j] & 0xffffu);
                    kr[i * 8 + j * 2 + 1] = bf2f(w[j] >> 16);
                }
            }
        }
#pragma unroll
        for (int j = 0; j < UB; j++) {
            float dot = 0.f;
#pragma unroll
            for (int d = 0; d < DD; d++) dot += qr[j][d] * kr[d];
            sc[j][kk] = dot * SCL;
        }
    }
    __syncthreads();

    // softmax per j: wave j owns row j
    {
        int j = wid;
        float mx = -INFINITY;
        for (int kk = lane; kk < SLK; kk += 64) mx = fmaxf(mx, sc[j][kk]);
#pragma unroll
        for (int off = 32; off > 0; off >>= 1) mx = fmaxf(mx, __shfl_xor(mx, off));
        float sm = 0.f;
        for (int kk = lane; kk < SLK; kk += 64) {
            float e = expf(sc[j][kk] - mx);
            sc[j][kk] = e;
            sm += e;
        }
#pragma unroll
        for (int off = 32; off > 0; off >>= 1) sm += __shfl_xor(sm, off);
        if (lane == 0) dinv[j] = 1.0f / sm;
    }
    __syncthreads();

    // attn @ V: thread (d = lane, c = wid) strides rows by 4
    {
        int d = lane, c = wid;
        float acc[UB] = {0.f, 0.f, 0.f, 0.f};
        for (int kk = c; kk < SLK; kk += 4) {
            float vv = le(v, (((size_t)(b * SLK + kk)) * NH + h) * DD + d, f32);
#pragma unroll
            for (int j = 0; j < UB; j++) acc[j] += sc[j][kk] * vv;
        }
#pragma unroll
        for (int j = 0; j < UB; j++) part[c * UB + j][d] = acc[j];
    }
    __syncthreads();
    {
        int j = t >> 6, d = t & 63;
        float tot = part[0 * UB + j][d] + part[1 * UB + j][d] +
                    part[2 * UB + j][d] + part[3 * UB + j][d];
        se(out, (((size_t)(b * SLQ + lqs[j])) * NH + h) * DD + d, f32, tot * dinv[j]);
    }
}

extern "C" void kernel_launch(void* const* d_in, const int* in_sizes, int n_in,
                              void* d_out, int out_size, void* d_ws, size_t ws_size,
                              hipStream_t stream)
{
    const void* q = d_in[0];
    const void* k = d_in[1];
    const void* v = d_in[2];
    const int* isamp = (const int*)d_in[3];

    // d_ws layout (tiny): topidx 5120 B, flag 4 B
    int* topidx = (int*)d_ws;
    int* flag   = (int*)((char*)d_ws + 5120);
    // M scratch in d_out (first 256 KB), consumed by k_topk before k_scan
    // overwrites the whole output buffer.
    float* M = (float*)d_out;

    k_probe  <<<1,                      64, 0, stream>>>((const unsigned int*)q, flag);
    k_sampleM<<<(NB * NH * SLQ) / 256, 256, 0, stream>>>(q, k, isamp, flag, M);
    k_topk   <<<NB * NH,               256, 0, stream>>>(M, topidx);
    k_scan   <<<NB * NH * NCH,         256, 0, stream>>>(v, flag, d_out);
    k_attn   <<<NB * NH * (NTOP / UB), 256, 0, stream>>>(q, k, v, topidx, flag, d_out);
}

// Round 4
// 327.849 us; speedup vs baseline: 2.0759x; 2.0759x over previous
//
#include <hip/hip_runtime.h>
#include <hip/hip_bf16.h>
#include <math.h>

#define NB 4
#define NH 8
#define SLQ 2048
#define SLK 2048
#define DD 64
#define SK 40
#define NTOP 40
#define SCL 0.125f
#define CH 128
#define NCH (SLK / CH) /* 16 */
#define UB 2            /* queries per k_attn block */
#define NUG (NTOP / UB) /* 20 */

typedef unsigned short ushort_t;

__device__ __forceinline__ float bf2f(unsigned int u16) {
    union { unsigned int i; float f; } v;
    v.i = u16 << 16;
    return v.f;
}
__device__ __forceinline__ ushort_t f2bf(float f) {
    union { float f; unsigned int i; } v;
    v.f = f;
    unsigned int x = v.i;
    unsigned int r = (x + 0x7FFFu + ((x >> 16) & 1u)) >> 16;  // RNE
    return (ushort_t)r;
}
template <bool F32>
__device__ __forceinline__ float le(const void* p, size_t i) {
    return F32 ? ((const float*)p)[i] : bf2f(((const ushort_t*)p)[i]);
}
template <bool F32>
__device__ __forceinline__ void se(void* p, size_t i, float v) {
    if (F32) ((float*)p)[i] = v;
    else ((ushort_t*)p)[i] = f2bf(v);
}
// load 8 consecutive elements starting at elem_off (must be 8-aligned)
template <bool F32>
__device__ __forceinline__ void load8(const void* p, size_t elem_off, float* r) {
    if (F32) {
        const float4* q = (const float4*)((const float*)p + elem_off);
        float4 a = q[0], b = q[1];
        r[0] = a.x; r[1] = a.y; r[2] = a.z; r[3] = a.w;
        r[4] = b.x; r[5] = b.y; r[6] = b.z; r[7] = b.w;
    } else {
        uint4 u = *(const uint4*)((const ushort_t*)p + elem_off);
        unsigned int w[4] = {u.x, u.y, u.z, u.w};
#pragma unroll
        for (int j = 0; j < 4; j++) {
            r[2 * j + 0] = bf2f(w[j] & 0xffffu);
            r[2 * j + 1] = bf2f(w[j] >> 16);
        }
    }
}

// -------------------------------------------------- K0: dtype probe
__global__ void k_probe(const unsigned int* __restrict__ qw, int* __restrict__ flag)
{
    int t = threadIdx.x;  // 64 threads
    unsigned int w = qw[t * 37];
    int cnt = 0;
#pragma unroll
    for (int s = 0; s < 2; s++) {
        unsigned int h = (s == 0) ? (w & 0xffffu) : (w >> 16);
        unsigned int e = (h >> 7) & 0xffu;
        int ok = (e == 0) ? ((h & 0x7fu) == 0) : (e >= 100 && e <= 153);
        cnt += ok;
    }
#pragma unroll
    for (int off = 32; off > 0; off >>= 1) cnt += __shfl_xor(cnt, off);
    if (t == 0) flag[0] = (cnt >= 104) ? 0 : 1;
}

// -------------------------------------------------- K1: sampled M (wave per query)
template <bool F32>
__device__ __forceinline__ void sampleM_body(
    const void* q, const void* k, const int* isamp, float* M)
{
    int t = threadIdx.x;
    int lane = t & 63;
    int gw = blockIdx.x * 4 + (t >> 6);   // global wave = (b*NH+h)*SLQ + l
    int l  = gw & (SLQ - 1);
    int bh = gw >> 11;
    int h  = bh & (NH - 1);
    int b  = bh >> 3;
    int sl = lane >> 3, c = lane & 7;

    float q8[8];
    load8<F32>(q, (((size_t)(b * SLQ + l)) * NH + h) * DD + c * 8, q8);
    int il = (lane < SK) ? (isamp[l * SK + lane] & (SLK - 1)) : 0;

    float mx = -INFINITY, sm = 0.f;
#pragma unroll
    for (int it = 0; it < SK / 8; it++) {
        int s = it * 8 + sl;
        int ks = __shfl(il, s);
        float k8[8];
        load8<F32>(k, (((size_t)(b * SLK + ks)) * NH + h) * DD + c * 8, k8);
        float dot = 0.f;
#pragma unroll
        for (int j = 0; j < 8; j++) dot += q8[j] * k8[j];
#pragma unroll
        for (int m = 1; m <= 4; m <<= 1) dot += __shfl_xor(dot, m);
        mx = fmaxf(mx, dot);
        sm += dot;
    }
#pragma unroll
    for (int m = 8; m <= 32; m <<= 1) {
        mx = fmaxf(mx, __shfl_xor(mx, m));
        sm += __shfl_xor(sm, m);
    }
    if (lane == 0) M[gw] = mx - sm * (1.0f / SK);
}
__global__ __launch_bounds__(256) void k_sampleM(
    const void* __restrict__ q, const void* __restrict__ k,
    const int* __restrict__ isamp, const int* __restrict__ flag,
    float* __restrict__ M)
{
    if (flag[0]) sampleM_body<true>(q, k, isamp, M);
    else         sampleM_body<false>(q, k, isamp, M);
}

// -------------------------------------------------- K2: top-40 (NaN-proof)
__global__ __launch_bounds__(256) void k_topk(
    const float* __restrict__ M, int* __restrict__ topidx)
{
    int bh = blockIdx.x;
    int t = threadIdx.x;
    int lane = t & 63, wid = t >> 6;
    __shared__ float vals[SLQ];
    __shared__ float wbv[4];
    __shared__ int   wbi[4];
    const float* Mp = M + (size_t)bh * SLQ;
    for (int i = t; i < SLQ; i += 256) vals[i] = Mp[i];
    __syncthreads();
    for (int u = 0; u < NTOP; u++) {
        float bv = -INFINITY; int bi = t;  // in-range even if all NaN
        for (int i = t; i < SLQ; i += 256) {
            float v = vals[i];
            if (v > bv) { bv = v; bi = i; }  // ascending scan keeps lowest i on tie
        }
#pragma unroll
        for (int off = 32; off > 0; off >>= 1) {
            float ov = __shfl_xor(bv, off);
            int   oi = __shfl_xor(bi, off);
            if (ov > bv || (ov == bv && oi < bi)) { bv = ov; bi = oi; }
        }
        if (lane == 0) { wbv[wid] = bv; wbi[wid] = bi; }
        __syncthreads();
        if (t == 0) {
            float fv = wbv[0]; int fi = wbi[0];
#pragma unroll
            for (int w = 1; w < 4; w++) {
                if (wbv[w] > fv || (wbv[w] == fv && wbi[w] < fi)) { fv = wbv[w]; fi = wbi[w]; }
            }
            fi &= (SLQ - 1);
            topidx[bh * NTOP + u] = fi;
            vals[fi] = -INFINITY;
        }
        __syncthreads();
    }
}

// -------------------------------------------------- K3: cumsum -> out (ALL rows)
template <bool F32>
__device__ __forceinline__ void scan_body(const void* v, void* out)
{
    int gid = blockIdx.x;
    int ch = gid & (NCH - 1);
    int bh = gid >> 4;
    int h = bh & 7, b = bh >> 3;
    int t = threadIdx.x;
    int d = t & 63, g = t >> 6;

    float ps = 0.f;
    int nprior = ch * CH;
    for (int r = g; r < nprior; r += 4)
        ps += le<F32>(v, (((size_t)(b * SLK + r)) * NH + h) * DD + d);

    float pre[32];
    float run = 0.f;
    int base_row = ch * CH + g * 32;
#pragma unroll 4
    for (int i = 0; i < 32; i++) {
        run += le<F32>(v, (((size_t)(b * SLK + base_row + i)) * NH + h) * DD + d);
        pre[i] = run;
    }

    __shared__ float pgsum[4][DD];
    __shared__ float qsum[4][DD];
    pgsum[g][d] = ps;
    qsum[g][d] = run;
    __syncthreads();

    float base = pgsum[0][d] + pgsum[1][d] + pgsum[2][d] + pgsum[3][d];
    for (int qq = 0; qq < g; qq++) base += qsum[qq][d];

#pragma unroll 4
    for (int i = 0; i < 32; i++) {
        se<F32>(out, (((size_t)(b * SLQ + base_row + i)) * NH + h) * DD + d, base + pre[i]);
    }
}
__global__ __launch_bounds__(256) void k_scan(
    const void* __restrict__ v, const int* __restrict__ flag, void* __restrict__ out)
{
    if (flag[0]) scan_body<true>(v, out);
    else         scan_body<false>(v, out);
}

// -------------------------------------------------- K4: attention rows
// 512 threads (8 waves), UB=2 queries per block, grid = 32*20 = 640
template <bool F32>
__device__ __forceinline__ void attn_body(
    const void* q, const void* k, const void* v,
    const int* topidx, void* out)
{
    int gid = blockIdx.x;
    int ug = gid % NUG;
    int bh = gid / NUG;
    int h  = bh & 7, b = bh >> 3;
    int t  = threadIdx.x;
    int lane = t & 63, w = t >> 6;       // 8 waves
    int sl = lane >> 3, c = lane & 7;

    __shared__ float sc[UB][SLK];        // 16 KB
    __shared__ float wred[8][UB];
    __shared__ float gm[UB];
    __shared__ float dinv[UB];
    __shared__ int   lqs[UB];
    __shared__ float part[8][UB][DD];    // 4 KB

    if (t < UB) lqs[t] = topidx[bh * NTOP + ug * UB + t] & (SLQ - 1);
    __syncthreads();

    float q8[UB][8];
#pragma unroll
    for (int j = 0; j < UB; j++)
        load8<F32>(q, (((size_t)(b * SLQ + lqs[j])) * NH + h) * DD + c * 8, q8[j]);

    // phase 1: scores (wave w owns keys [w*256, w*256+256))
#pragma unroll 2
    for (int it = 0; it < 32; it++) {
        int key = w * 256 + it * 8 + sl;
        float k8[8];
        load8<F32>(k, (((size_t)(b * SLK + key)) * NH + h) * DD + c * 8, k8);
#pragma unroll
        for (int j = 0; j < UB; j++) {
            float dot = 0.f;
#pragma unroll
            for (int x = 0; x < 8; x++) dot += q8[j][x] * k8[x];
#pragma unroll
            for (int m = 1; m <= 4; m <<= 1) dot += __shfl_xor(dot, m);
            if (c == j) sc[j][key] = dot * SCL;
        }
    }
    __syncthreads();

    // phase 2: softmax over 2048 per query
#pragma unroll
    for (int j = 0; j < UB; j++) {
        float m = -INFINITY;
#pragma unroll
        for (int i = 0; i < 4; i++) m = fmaxf(m, sc[j][w * 256 + i * 64 + lane]);
#pragma unroll
        for (int mm = 1; mm <= 32; mm <<= 1) m = fmaxf(m, __shfl_xor(m, mm));
        if (lane == 0) wred[w][j] = m;
    }
    __syncthreads();
    if (t < UB) {
        float m = -INFINITY;
#pragma unroll
        for (int w2 = 0; w2 < 8; w2++) m = fmaxf(m, wred[w2][t]);
        gm[t] = m;
    }
    __syncthreads();
#pragma unroll
    for (int j = 0; j < UB; j++) {
        float m = gm[j];
        float s = 0.f;
#pragma unroll
        for (int i = 0; i < 4; i++) {
            int idx = w * 256 + i * 64 + lane;
            float e = expf(sc[j][idx] - m);
            sc[j][idx] = e;
            s += e;
        }
#pragma unroll
        for (int mm = 1; mm <= 32; mm <<= 1) s += __shfl_xor(s, mm);
        if (lane == 0) wred[w][j] = s;
    }
    __syncthreads();
    if (t < UB) {
        float s = 0.f;
#pragma unroll
        for (int w2 = 0; w2 < 8; w2++) s += wred[w2][t];
        dinv[t] = 1.0f / s;
    }
    __syncthreads();

    // phase 3: PV (lane = d, waves interleave keys)
    {
        int d = lane;
        float acc[UB] = {0.f, 0.f};
        for (int i = 0; i < 256; i++) {
            int key = w + i * 8;
            float vv = le<F32>(v, (((size_t)(b * SLK + key)) * NH + h) * DD + d);
#pragma unroll
            for (int j = 0; j < UB; j++) acc[j] += sc[j][key] * vv;
        }
#pragma unroll
        for (int j = 0; j < UB; j++) part[w][j][d] = acc[j];
    }
    __syncthreads();
    if (t < UB * DD) {
        int j = t >> 6, d = t & 63;
        float tot = 0.f;
#pragma unroll
        for (int w2 = 0; w2 < 8; w2++) tot += part[w2][j][d];
        se<F32>(out, (((size_t)(b * SLQ + lqs[j])) * NH + h) * DD + d, tot * dinv[j]);
    }
}
__global__ __launch_bounds__(512) void k_attn(
    const void* __restrict__ q, const void* __restrict__ k,
    const void* __restrict__ v, const int* __restrict__ topidx,
    const int* __restrict__ flag, void* __restrict__ out)
{
    if (flag[0]) attn_body<true>(q, k, v, topidx, out);
    else         attn_body<false>(q, k, v, topidx, out);
}

extern "C" void kernel_launch(void* const* d_in, const int* in_sizes, int n_in,
                              void* d_out, int out_size, void* d_ws, size_t ws_size,
                              hipStream_t stream)
{
    const void* q = d_in[0];
    const void* k = d_in[1];
    const void* v = d_in[2];
    const int* isamp = (const int*)d_in[3];

    int* topidx = (int*)d_ws;                    // 5120 B
    int* flag   = (int*)((char*)d_ws + 5120);    // 4 B
    float* M = (float*)d_out;                    // 256 KB scratch, overwritten by k_scan

    k_probe  <<<1,                       64, 0, stream>>>((const unsigned int*)q, flag);
    k_sampleM<<<(NB * NH * SLQ) / 4,    256, 0, stream>>>(q, k, isamp, flag, M);
    k_topk   <<<NB * NH,                256, 0, stream>>>(M, topidx);
    k_scan   <<<NB * NH * NCH,          256, 0, stream>>>(v, flag, d_out);
    k_attn   <<<NB * NH * NUG,          512, 0, stream>>>(q, k, v, topidx, flag, d_out);
}

// Round 5
// 303.492 us; speedup vs baseline: 2.2425x; 1.0803x over previous
//
#include <hip/hip_runtime.h>
#include <hip/hip_bf16.h>
#include <math.h>

#define NB 4
#define NH 8
#define SLQ 2048
#define SLK 2048
#define DD 64
#define SK 40
#define NTOP 40
#define SCL 0.125f
#define CH 128
#define NCH (SLK / CH) /* 16 */
#define UB 2            /* queries per k_attn block */
#define NUG (NTOP / UB) /* 20 */

typedef unsigned short ushort_t;

__device__ __forceinline__ float bf2f(unsigned int u16) {
    union { unsigned int i; float f; } v;
    v.i = u16 << 16;
    return v.f;
}
__device__ __forceinline__ ushort_t f2bf(float f) {
    union { float f; unsigned int i; } v;
    v.f = f;
    unsigned int x = v.i;
    unsigned int r = (x + 0x7FFFu + ((x >> 16) & 1u)) >> 16;  // RNE
    return (ushort_t)r;
}
template <bool F32>
__device__ __forceinline__ float le(const void* p, size_t i) {
    return F32 ? ((const float*)p)[i] : bf2f(((const ushort_t*)p)[i]);
}
template <bool F32>
__device__ __forceinline__ void se(void* p, size_t i, float v) {
    if (F32) ((float*)p)[i] = v;
    else ((ushort_t*)p)[i] = f2bf(v);
}
// 4 consecutive elements at elem_off (4-aligned)
template <bool F32>
__device__ __forceinline__ float4 load4(const void* p, size_t off) {
    if (F32) return *(const float4*)((const float*)p + off);
    uint2 u = *(const uint2*)((const ushort_t*)p + off);
    float4 r;
    r.x = bf2f(u.x & 0xffffu); r.y = bf2f(u.x >> 16);
    r.z = bf2f(u.y & 0xffffu); r.w = bf2f(u.y >> 16);
    return r;
}
template <bool F32>
__device__ __forceinline__ void store4(void* p, size_t off, float4 v) {
    if (F32) { *(float4*)((float*)p + off) = v; return; }
    uint2 u;
    u.x = (unsigned)f2bf(v.x) | ((unsigned)f2bf(v.y) << 16);
    u.y = (unsigned)f2bf(v.z) | ((unsigned)f2bf(v.w) << 16);
    *(uint2*)((ushort_t*)p + off) = u;
}
// 8 consecutive elements at elem_off (8-aligned)
template <bool F32>
__device__ __forceinline__ void load8(const void* p, size_t elem_off, float* r) {
    if (F32) {
        const float4* q = (const float4*)((const float*)p + elem_off);
        float4 a = q[0], b = q[1];
        r[0] = a.x; r[1] = a.y; r[2] = a.z; r[3] = a.w;
        r[4] = b.x; r[5] = b.y; r[6] = b.z; r[7] = b.w;
    } else {
        uint4 u = *(const uint4*)((const ushort_t*)p + elem_off);
        unsigned int w[4] = {u.x, u.y, u.z, u.w};
#pragma unroll
        for (int j = 0; j < 4; j++) {
            r[2 * j + 0] = bf2f(w[j] & 0xffffu);
            r[2 * j + 1] = bf2f(w[j] >> 16);
        }
    }
}

// -------------------------------------------------- K0: dtype probe
__global__ void k_probe(const unsigned int* __restrict__ qw, int* __restrict__ flag)
{
    int t = threadIdx.x;  // 64 threads
    unsigned int w = qw[t * 37];
    int cnt = 0;
#pragma unroll
    for (int s = 0; s < 2; s++) {
        unsigned int h = (s == 0) ? (w & 0xffffu) : (w >> 16);
        unsigned int e = (h >> 7) & 0xffu;
        int ok = (e == 0) ? ((h & 0x7fu) == 0) : (e >= 100 && e <= 153);
        cnt += ok;
    }
#pragma unroll
    for (int off = 32; off > 0; off >>= 1) cnt += __shfl_xor(cnt, off);
    if (t == 0) flag[0] = (cnt >= 104) ? 0 : 1;
}

// -------------------------------------------------- K1: sampled M (wave per query)
template <bool F32>
__device__ __forceinline__ void sampleM_body(
    const void* q, const void* k, const int* isamp, float* M)
{
    int t = threadIdx.x;
    int lane = t & 63;
    int gw = blockIdx.x * 4 + (t >> 6);   // global wave = (b*NH+h)*SLQ + l
    int l  = gw & (SLQ - 1);
    int bh = gw >> 11;
    int h  = bh & (NH - 1);
    int b  = bh >> 3;
    int sl = lane >> 3, c = lane & 7;

    float q8[8];
    load8<F32>(q, (((size_t)(b * SLQ + l)) * NH + h) * DD + c * 8, q8);
    int il = (lane < SK) ? (isamp[l * SK + lane] & (SLK - 1)) : 0;

    float mx = -INFINITY, sm = 0.f;
#pragma unroll
    for (int it = 0; it < SK / 8; it++) {
        int s = it * 8 + sl;
        int ks = __shfl(il, s);
        float k8[8];
        load8<F32>(k, (((size_t)(b * SLK + ks)) * NH + h) * DD + c * 8, k8);
        float dot = 0.f;
#pragma unroll
        for (int j = 0; j < 8; j++) dot += q8[j] * k8[j];
#pragma unroll
        for (int m = 1; m <= 4; m <<= 1) dot += __shfl_xor(dot, m);
        mx = fmaxf(mx, dot);
        sm += dot;
    }
#pragma unroll
    for (int m = 8; m <= 32; m <<= 1) {
        mx = fmaxf(mx, __shfl_xor(mx, m));
        sm += __shfl_xor(sm, m);
    }
    if (lane == 0) M[gw] = mx - sm * (1.0f / SK);
}
__global__ __launch_bounds__(256) void k_sampleM(
    const void* __restrict__ q, const void* __restrict__ k,
    const int* __restrict__ isamp, const int* __restrict__ flag,
    float* __restrict__ M)
{
    if (flag[0]) sampleM_body<true>(q, k, isamp, M);
    else         sampleM_body<false>(q, k, isamp, M);
}

// -------------------------------------------------- K2: top-40 (NaN-proof)
__global__ __launch_bounds__(256) void k_topk(
    const float* __restrict__ M, int* __restrict__ topidx)
{
    int bh = blockIdx.x;
    int t = threadIdx.x;
    int lane = t & 63, wid = t >> 6;
    __shared__ float vals[SLQ];
    __shared__ float wbv[4];
    __shared__ int   wbi[4];
    const float* Mp = M + (size_t)bh * SLQ;
    for (int i = t; i < SLQ; i += 256) vals[i] = Mp[i];
    __syncthreads();
    for (int u = 0; u < NTOP; u++) {
        float bv = -INFINITY; int bi = t;  // in-range even if all NaN
        for (int i = t; i < SLQ; i += 256) {
            float v = vals[i];
            if (v > bv) { bv = v; bi = i; }
        }
#pragma unroll
        for (int off = 32; off > 0; off >>= 1) {
            float ov = __shfl_xor(bv, off);
            int   oi = __shfl_xor(bi, off);
            if (ov > bv || (ov == bv && oi < bi)) { bv = ov; bi = oi; }
        }
        if (lane == 0) { wbv[wid] = bv; wbi[wid] = bi; }
        __syncthreads();
        if (t == 0) {
            float fv = wbv[0]; int fi = wbi[0];
#pragma unroll
            for (int w = 1; w < 4; w++) {
                if (wbv[w] > fv || (wbv[w] == fv && wbi[w] < fi)) { fv = wbv[w]; fi = wbi[w]; }
            }
            fi &= (SLQ - 1);
            topidx[bh * NTOP + u] = fi;
            vals[fi] = -INFINITY;
        }
        __syncthreads();
    }
}

// -------------------------------------------------- K3a: per-chunk column sums
// block=(bh,ch), thread: q4=t&15 (4 cols), g=t>>4 (8 rows)
template <bool F32>
__device__ __forceinline__ void csum_body(const void* v, float* bsum)
{
    int gid = blockIdx.x;
    int ch = gid & (NCH - 1);
    int bh = gid >> 4;
    int h = bh & 7, b = bh >> 3;
    int t = threadIdx.x;
    int q4 = t & 15, g = t >> 4;
    int base_row = ch * CH + g * 8;

    float4 s = {0.f, 0.f, 0.f, 0.f};
#pragma unroll
    for (int i = 0; i < 8; i++) {
        float4 a = load4<F32>(v, (((size_t)(b * SLK + base_row + i)) * NH + h) * DD + q4 * 4);
        s.x += a.x; s.y += a.y; s.z += a.z; s.w += a.w;
    }
    __shared__ float4 gs[16][16];
    gs[g][q4] = s;
    __syncthreads();
    if (t < 16) {
        float4 tot = gs[0][t];
#pragma unroll
        for (int g2 = 1; g2 < 16; g2++) {
            tot.x += gs[g2][t].x; tot.y += gs[g2][t].y;
            tot.z += gs[g2][t].z; tot.w += gs[g2][t].w;
        }
        *(float4*)&bsum[(size_t)gid * DD + t * 4] = tot;
    }
}
__global__ __launch_bounds__(256) void k_csum(
    const void* __restrict__ v, const int* __restrict__ flag, float* __restrict__ bsum)
{
    if (flag[0]) csum_body<true>(v, bsum);
    else         csum_body<false>(v, bsum);
}

// -------------------------------------------------- K3b: scan using chunk sums
template <bool F32>
__device__ __forceinline__ void scanf_body(const void* v, const float* bsum, void* out)
{
    int gid = blockIdx.x;
    int ch = gid & (NCH - 1);
    int bh = gid >> 4;
    int h = bh & 7, b = bh >> 3;
    int t = threadIdx.x;
    int q4 = t & 15, g = t >> 4;
    int base_row = ch * CH + g * 8;

    float4 pre[8];
    float4 run = {0.f, 0.f, 0.f, 0.f};
#pragma unroll
    for (int i = 0; i < 8; i++) {
        float4 a = load4<F32>(v, (((size_t)(b * SLK + base_row + i)) * NH + h) * DD + q4 * 4);
        run.x += a.x; run.y += a.y; run.z += a.z; run.w += a.w;
        pre[i] = run;
    }
    __shared__ float4 gs[16][16];
    gs[g][q4] = run;
    __syncthreads();

    float4 base = {0.f, 0.f, 0.f, 0.f};
    for (int c = 0; c < ch; c++) {
        float4 a = *(const float4*)&bsum[((size_t)bh * NCH + c) * DD + q4 * 4];
        base.x += a.x; base.y += a.y; base.z += a.z; base.w += a.w;
    }
    for (int g2 = 0; g2 < g; g2++) {
        float4 a = gs[g2][q4];
        base.x += a.x; base.y += a.y; base.z += a.z; base.w += a.w;
    }
#pragma unroll
    for (int i = 0; i < 8; i++) {
        float4 o = {base.x + pre[i].x, base.y + pre[i].y,
                    base.z + pre[i].z, base.w + pre[i].w};
        store4<F32>(out, (((size_t)(b * SLQ + base_row + i)) * NH + h) * DD + q4 * 4, o);
    }
}
__global__ __launch_bounds__(256) void k_scan_fast(
    const void* __restrict__ v, const float* __restrict__ bsum,
    const int* __restrict__ flag, void* __restrict__ out)
{
    if (flag[0]) scanf_body<true>(v, bsum, out);
    else         scanf_body<false>(v, bsum, out);
}

// -------------------------------------------------- K3-slow: ws-less fallback
template <bool F32>
__device__ __forceinline__ void scans_body(const void* v, void* out)
{
    int gid = blockIdx.x;
    int ch = gid & (NCH - 1);
    int bh = gid >> 4;
    int h = bh & 7, b = bh >> 3;
    int t = threadIdx.x;
    int q4 = t & 15, g = t >> 4;

    __shared__ float4 pa[16][16];
    __shared__ float4 gs[16][16];

    float4 ps = {0.f, 0.f, 0.f, 0.f};
    int nprior = ch * CH;
    for (int r = g; r < nprior; r += 16) {
        float4 a = load4<F32>(v, (((size_t)(b * SLK + r)) * NH + h) * DD + q4 * 4);
        ps.x += a.x; ps.y += a.y; ps.z += a.z; ps.w += a.w;
    }
    pa[g][q4] = ps;

    int base_row = ch * CH + g * 8;
    float4 pre[8];
    float4 run = {0.f, 0.f, 0.f, 0.f};
#pragma unroll
    for (int i = 0; i < 8; i++) {
        float4 a = load4<F32>(v, (((size_t)(b * SLK + base_row + i)) * NH + h) * DD + q4 * 4);
        run.x += a.x; run.y += a.y; run.z += a.z; run.w += a.w;
        pre[i] = run;
    }
    gs[g][q4] = run;
    __syncthreads();

    float4 base = {0.f, 0.f, 0.f, 0.f};
#pragma unroll
    for (int g2 = 0; g2 < 16; g2++) {
        float4 a = pa[g2][q4];
        base.x += a.x; base.y += a.y; base.z += a.z; base.w += a.w;
    }
    for (int g2 = 0; g2 < g; g2++) {
        float4 a = gs[g2][q4];
        base.x += a.x; base.y += a.y; base.z += a.z; base.w += a.w;
    }
#pragma unroll
    for (int i = 0; i < 8; i++) {
        float4 o = {base.x + pre[i].x, base.y + pre[i].y,
                    base.z + pre[i].z, base.w + pre[i].w};
        store4<F32>(out, (((size_t)(b * SLQ + base_row + i)) * NH + h) * DD + q4 * 4, o);
    }
}
__global__ __launch_bounds__(256) void k_scan_slow(
    const void* __restrict__ v, const int* __restrict__ flag, void* __restrict__ out)
{
    if (flag[0]) scans_body<true>(v, out);
    else         scans_body<false>(v, out);
}

// -------------------------------------------------- K4: attention rows
template <bool F32>
__device__ __forceinline__ void attn_body(
    const void* q, const void* k, const void* v,
    const int* topidx, void* out)
{
    int gid = blockIdx.x;
    int ug = gid % NUG;
    int bh = gid / NUG;
    int h  = bh & 7, b = bh >> 3;
    int t  = threadIdx.x;
    int lane = t & 63, w = t >> 6;       // 8 waves
    int sl = lane >> 3, c = lane & 7;

    __shared__ float sc[UB][SLK];        // 16 KB
    __shared__ float wred[8][UB];
    __shared__ float gm[UB];
    __shared__ float dinv[UB];
    __shared__ int   lqs[UB];
    __shared__ float part[8][UB][DD];    // 4 KB

    if (t < UB) lqs[t] = topidx[bh * NTOP + ug * UB + t] & (SLQ - 1);
    __syncthreads();

    float q8[UB][8];
#pragma unroll
    for (int j = 0; j < UB; j++)
        load8<F32>(q, (((size_t)(b * SLQ + lqs[j])) * NH + h) * DD + c * 8, q8[j]);

    // phase 1: scores (wave w owns keys [w*256, w*256+256))
#pragma unroll 2
    for (int it = 0; it < 32; it++) {
        int key = w * 256 + it * 8 + sl;
        float k8[8];
        load8<F32>(k, (((size_t)(b * SLK + key)) * NH + h) * DD + c * 8, k8);
#pragma unroll
        for (int j = 0; j < UB; j++) {
            float dot = 0.f;
#pragma unroll
            for (int x = 0; x < 8; x++) dot += q8[j][x] * k8[x];
#pragma unroll
            for (int m = 1; m <= 4; m <<= 1) dot += __shfl_xor(dot, m);
            if (c == j) sc[j][key] = dot * SCL;
        }
    }
    __syncthreads();

    // phase 2: softmax over 2048 per query
#pragma unroll
    for (int j = 0; j < UB; j++) {
        float m = -INFINITY;
#pragma unroll
        for (int i = 0; i < 4; i++) m = fmaxf(m, sc[j][w * 256 + i * 64 + lane]);
#pragma unroll
        for (int mm = 1; mm <= 32; mm <<= 1) m = fmaxf(m, __shfl_xor(m, mm));
        if (lane == 0) wred[w][j] = m;
    }
    __syncthreads();
    if (t < UB) {
        float m = -INFINITY;
#pragma unroll
        for (int w2 = 0; w2 < 8; w2++) m = fmaxf(m, wred[w2][t]);
        gm[t] = m;
    }
    __syncthreads();
#pragma unroll
    for (int j = 0; j < UB; j++) {
        float m = gm[j];
        float s = 0.f;
#pragma unroll
        for (int i = 0; i < 4; i++) {
            int idx = w * 256 + i * 64 + lane;
            float e = expf(sc[j][idx] - m);
            sc[j][idx] = e;
            s += e;
        }
#pragma unroll
        for (int mm = 1; mm <= 32; mm <<= 1) s += __shfl_xor(s, mm);
        if (lane == 0) wred[w][j] = s;
    }
    __syncthreads();
    if (t < UB) {
        float s = 0.f;
#pragma unroll
        for (int w2 = 0; w2 < 8; w2++) s += wred[w2][t];
        dinv[t] = 1.0f / s;
    }
    __syncthreads();

    // phase 3: PV vectorized — thread = (4 cols, row-phase r), wave covers 4 keys/iter
    {
        int l16 = lane & 15, r = lane >> 4;
        float4 acc[UB];
#pragma unroll
        for (int j = 0; j < UB; j++) acc[j] = {0.f, 0.f, 0.f, 0.f};
        for (int i = 0; i < 64; i++) {
            int key = w + (i * 4 + r) * 8;
            float4 v4 = load4<F32>(v, (((size_t)(b * SLK + key)) * NH + h) * DD + l16 * 4);
#pragma unroll
            for (int j = 0; j < UB; j++) {
                float sj = sc[j][key];
                acc[j].x += sj * v4.x; acc[j].y += sj * v4.y;
                acc[j].z += sj * v4.z; acc[j].w += sj * v4.w;
            }
        }
#pragma unroll
        for (int j = 0; j < UB; j++) {
#pragma unroll
            for (int mm = 16; mm <= 32; mm <<= 1) {
                acc[j].x += __shfl_xor(acc[j].x, mm);
                acc[j].y += __shfl_xor(acc[j].y, mm);
                acc[j].z += __shfl_xor(acc[j].z, mm);
                acc[j].w += __shfl_xor(acc[j].w, mm);
            }
            if (r == 0) *(float4*)&part[w][j][l16 * 4] = acc[j];
        }
    }
    __syncthreads();
    if (t < UB * DD) {
        int j = t >> 6, d = t & 63;
        float tot = 0.f;
#pragma unroll
        for (int w2 = 0; w2 < 8; w2++) tot += part[w2][j][d];
        se<F32>(out, (((size_t)(b * SLQ + lqs[j])) * NH + h) * DD + d, tot * dinv[j]);
    }
}
__global__ __launch_bounds__(512) void k_attn(
    const void* __restrict__ q, const void* __restrict__ k,
    const void* __restrict__ v, const int* __restrict__ topidx,
    const int* __restrict__ flag, void* __restrict__ out)
{
    if (flag[0]) attn_body<true>(q, k, v, topidx, out);
    else         attn_body<false>(q, k, v, topidx, out);
}

extern "C" void kernel_launch(void* const* d_in, const int* in_sizes, int n_in,
                              void* d_out, int out_size, void* d_ws, size_t ws_size,
                              hipStream_t stream)
{
    const void* q = d_in[0];
    const void* k = d_in[1];
    const void* v = d_in[2];
    const int* isamp = (const int*)d_in[3];

    int* topidx = (int*)d_ws;                    // 5120 B
    int* flag   = (int*)((char*)d_ws + 5120);    // 4 B
    float* bsum = (float*)((char*)d_ws + 8192);  // 128 KB (optional)
    float* M = (float*)d_out;                    // 256 KB scratch, overwritten by scan

    const size_t need = 8192 + (size_t)NB * NH * NCH * DD * 4;
    const bool fast = ws_size >= need;           // constant across calls -> capture-safe

    k_probe  <<<1,                       64, 0, stream>>>((const unsigned int*)q, flag);
    k_sampleM<<<(NB * NH * SLQ) / 4,    256, 0, stream>>>(q, k, isamp, flag, M);
    k_topk   <<<NB * NH,                256, 0, stream>>>(M, topidx);
    if (fast) {
        k_csum     <<<NB * NH * NCH,    256, 0, stream>>>(v, flag, bsum);
        k_scan_fast<<<NB * NH * NCH,    256, 0, stream>>>(v, bsum, flag, d_out);
    } else {
        k_scan_slow<<<NB * NH * NCH,    256, 0, stream>>>(v, flag, d_out);
    }
    k_attn   <<<NB * NH * NUG,          512, 0, stream>>>(q, k, v, topidx, flag, d_out);
}

// Round 6
// 288.712 us; speedup vs baseline: 2.3573x; 1.0512x over previous
//
#include <hip/hip_runtime.h>
#include <hip/hip_bf16.h>
#include <math.h>

#define NB 4
#define NH 8
#define SLQ 2048
#define SLK 2048
#define DD 64
#define SK 40
#define NTOP 40
#define SCL 0.125f
#define CH 128
#define NCH (SLK / CH) /* 16 */
#define UB 2            /* queries per k_attn block */
#define NUG (NTOP / UB) /* 20 */
#define NBH (NB * NH)   /* 32 */

typedef unsigned short ushort_t;

__device__ __forceinline__ float bf2f(unsigned int u16) {
    union { unsigned int i; float f; } v;
    v.i = u16 << 16;
    return v.f;
}
__device__ __forceinline__ ushort_t f2bf(float f) {
    union { float f; unsigned int i; } v;
    v.f = f;
    unsigned int x = v.i;
    unsigned int r = (x + 0x7FFFu + ((x >> 16) & 1u)) >> 16;  // RNE
    return (ushort_t)r;
}
template <bool F32>
__device__ __forceinline__ float le(const void* p, size_t i) {
    return F32 ? ((const float*)p)[i] : bf2f(((const ushort_t*)p)[i]);
}
template <bool F32>
__device__ __forceinline__ void se(void* p, size_t i, float v) {
    if (F32) ((float*)p)[i] = v;
    else ((ushort_t*)p)[i] = f2bf(v);
}
template <bool F32>
__device__ __forceinline__ float4 load4(const void* p, size_t off) {
    if (F32) return *(const float4*)((const float*)p + off);
    uint2 u = *(const uint2*)((const ushort_t*)p + off);
    float4 r;
    r.x = bf2f(u.x & 0xffffu); r.y = bf2f(u.x >> 16);
    r.z = bf2f(u.y & 0xffffu); r.w = bf2f(u.y >> 16);
    return r;
}
template <bool F32>
__device__ __forceinline__ void store4(void* p, size_t off, float4 v) {
    if (F32) { *(float4*)((float*)p + off) = v; return; }
    uint2 u;
    u.x = (unsigned)f2bf(v.x) | ((unsigned)f2bf(v.y) << 16);
    u.y = (unsigned)f2bf(v.z) | ((unsigned)f2bf(v.w) << 16);
    *(uint2*)((ushort_t*)p + off) = u;
}
template <bool F32>
__device__ __forceinline__ void load8(const void* p, size_t elem_off, float* r) {
    if (F32) {
        const float4* q = (const float4*)((const float*)p + elem_off);
        float4 a = q[0], b = q[1];
        r[0] = a.x; r[1] = a.y; r[2] = a.z; r[3] = a.w;
        r[4] = b.x; r[5] = b.y; r[6] = b.z; r[7] = b.w;
    } else {
        uint4 u = *(const uint4*)((const ushort_t*)p + elem_off);
        unsigned int w[4] = {u.x, u.y, u.z, u.w};
#pragma unroll
        for (int j = 0; j < 4; j++) {
            r[2 * j + 0] = bf2f(w[j] & 0xffffu);
            r[2 * j + 1] = bf2f(w[j] >> 16);
        }
    }
}

// -------------------------------------------------- K0: dtype probe
__global__ void k_probe(const unsigned int* __restrict__ qw, int* __restrict__ flag)
{
    int t = threadIdx.x;  // 64 threads
    unsigned int w = qw[t * 37];
    int cnt = 0;
#pragma unroll
    for (int s = 0; s < 2; s++) {
        unsigned int h = (s == 0) ? (w & 0xffffu) : (w >> 16);
        unsigned int e = (h >> 7) & 0xffu;
        int ok = (e == 0) ? ((h & 0x7fu) == 0) : (e >= 100 && e <= 153);
        cnt += ok;
    }
#pragma unroll
    for (int off = 32; off > 0; off >>= 1) cnt += __shfl_xor(cnt, off);
    if (t == 0) flag[0] = (cnt >= 104) ? 0 : 1;
}

// -------------------------------------------------- K1: sampled M (wave per query)
// XCD swizzle: bh in low 5 bits of blockIdx -> same-bh blocks land on one XCD,
// keeping that (b,h) K-slice (512 KB x 4 b = 2 MB) resident in its L2.
template <bool F32>
__device__ __forceinline__ void sampleM_body(
    const void* q, const void* k, const int* isamp, float* M)
{
    int t = threadIdx.x;
    int lane = t & 63;
    int blk = blockIdx.x;                 // 16384 blocks
    int bh = blk & (NBH - 1);
    int lgrp = blk >> 5;                  // 0..511
    int l = lgrp * 4 + (t >> 6);
    int h  = bh & (NH - 1);
    int b  = bh >> 3;
    int sl = lane >> 3, c = lane & 7;

    float q8[8];
    load8<F32>(q, (((size_t)(b * SLQ + l)) * NH + h) * DD + c * 8, q8);
    int il = (lane < SK) ? (isamp[l * SK + lane] & (SLK - 1)) : 0;

    float mx = -INFINITY, sm = 0.f;
#pragma unroll
    for (int it = 0; it < SK / 8; it++) {
        int s = it * 8 + sl;
        int ks = __shfl(il, s);
        float k8[8];
        load8<F32>(k, (((size_t)(b * SLK + ks)) * NH + h) * DD + c * 8, k8);
        float dot = 0.f;
#pragma unroll
        for (int j = 0; j < 8; j++) dot += q8[j] * k8[j];
#pragma unroll
        for (int m = 1; m <= 4; m <<= 1) dot += __shfl_xor(dot, m);
        mx = fmaxf(mx, dot);
        sm += dot;
    }
#pragma unroll
    for (int m = 8; m <= 32; m <<= 1) {
        mx = fmaxf(mx, __shfl_xor(mx, m));
        sm += __shfl_xor(sm, m);
    }
    if (lane == 0) M[(size_t)bh * SLQ + l] = mx - sm * (1.0f / SK);
}
__global__ __launch_bounds__(256) void k_sampleM(
    const void* __restrict__ q, const void* __restrict__ k,
    const int* __restrict__ isamp, const int* __restrict__ flag,
    float* __restrict__ M)
{
    if (flag[0]) sampleM_body<true>(q, k, isamp, M);
    else         sampleM_body<false>(q, k, isamp, M);
}

// -------------------------------------------------- K2: top-40 (NaN-proof)
__global__ __launch_bounds__(256) void k_topk(
    const float* __restrict__ M, int* __restrict__ topidx)
{
    int bh = blockIdx.x;
    int t = threadIdx.x;
    int lane = t & 63, wid = t >> 6;
    __shared__ float vals[SLQ];
    __shared__ float wbv[4];
    __shared__ int   wbi[4];
    const float* Mp = M + (size_t)bh * SLQ;
    for (int i = t; i < SLQ; i += 256) vals[i] = Mp[i];
    __syncthreads();
    for (int u = 0; u < NTOP; u++) {
        float bv = -INFINITY; int bi = t;  // in-range even if all NaN
        for (int i = t; i < SLQ; i += 256) {
            float v = vals[i];
            if (v > bv) { bv = v; bi = i; }
        }
#pragma unroll
        for (int off = 32; off > 0; off >>= 1) {
            float ov = __shfl_xor(bv, off);
            int   oi = __shfl_xor(bi, off);
            if (ov > bv || (ov == bv && oi < bi)) { bv = ov; bi = oi; }
        }
        if (lane == 0) { wbv[wid] = bv; wbi[wid] = bi; }
        __syncthreads();
        if (t == 0) {
            float fv = wbv[0]; int fi = wbi[0];
#pragma unroll
            for (int w = 1; w < 4; w++) {
                if (wbv[w] > fv || (wbv[w] == fv && wbi[w] < fi)) { fv = wbv[w]; fi = wbi[w]; }
            }
            fi &= (SLQ - 1);
            topidx[bh * NTOP + u] = fi;
            vals[fi] = -INFINITY;
        }
        __syncthreads();
    }
}

// -------------------------------------------------- K3a: per-chunk column sums
// XCD swizzle: bh = gid & 31
template <bool F32>
__device__ __forceinline__ void csum_body(const void* v, float* bsum)
{
    int gid = blockIdx.x;
    int bh = gid & (NBH - 1);
    int ch = gid >> 5;
    int h = bh & 7, b = bh >> 3;
    int t = threadIdx.x;
    int q4 = t & 15, g = t >> 4;
    int base_row = ch * CH + g * 8;

    float4 s = {0.f, 0.f, 0.f, 0.f};
#pragma unroll
    for (int i = 0; i < 8; i++) {
        float4 a = load4<F32>(v, (((size_t)(b * SLK + base_row + i)) * NH + h) * DD + q4 * 4);
        s.x += a.x; s.y += a.y; s.z += a.z; s.w += a.w;
    }
    __shared__ float4 gs[16][16];
    gs[g][q4] = s;
    __syncthreads();
    if (t < 16) {
        float4 tot = gs[0][t];
#pragma unroll
        for (int g2 = 1; g2 < 16; g2++) {
            tot.x += gs[g2][t].x; tot.y += gs[g2][t].y;
            tot.z += gs[g2][t].z; tot.w += gs[g2][t].w;
        }
        *(float4*)&bsum[((size_t)bh * NCH + ch) * DD + t * 4] = tot;
    }
}
__global__ __launch_bounds__(256) void k_csum(
    const void* __restrict__ v, const int* __restrict__ flag, float* __restrict__ bsum)
{
    if (flag[0]) csum_body<true>(v, bsum);
    else         csum_body<false>(v, bsum);
}

// -------------------------------------------------- K3b: scan using chunk sums
template <bool F32>
__device__ __forceinline__ void scanf_body(const void* v, const float* bsum, void* out)
{
    int gid = blockIdx.x;
    int bh = gid & (NBH - 1);
    int ch = gid >> 5;
    int h = bh & 7, b = bh >> 3;
    int t = threadIdx.x;
    int q4 = t & 15, g = t >> 4;
    int base_row = ch * CH + g * 8;

    float4 pre[8];
    float4 run = {0.f, 0.f, 0.f, 0.f};
#pragma unroll
    for (int i = 0; i < 8; i++) {
        float4 a = load4<F32>(v, (((size_t)(b * SLK + base_row + i)) * NH + h) * DD + q4 * 4);
        run.x += a.x; run.y += a.y; run.z += a.z; run.w += a.w;
        pre[i] = run;
    }
    __shared__ float4 gs[16][16];
    gs[g][q4] = run;
    __syncthreads();

    float4 base = {0.f, 0.f, 0.f, 0.f};
    for (int c = 0; c < ch; c++) {
        float4 a = *(const float4*)&bsum[((size_t)bh * NCH + c) * DD + q4 * 4];
        base.x += a.x; base.y += a.y; base.z += a.z; base.w += a.w;
    }
    for (int g2 = 0; g2 < g; g2++) {
        float4 a = gs[g2][q4];
        base.x += a.x; base.y += a.y; base.z += a.z; base.w += a.w;
    }
#pragma unroll
    for (int i = 0; i < 8; i++) {
        float4 o = {base.x + pre[i].x, base.y + pre[i].y,
                    base.z + pre[i].z, base.w + pre[i].w};
        store4<F32>(out, (((size_t)(b * SLQ + base_row + i)) * NH + h) * DD + q4 * 4, o);
    }
}
__global__ __launch_bounds__(256) void k_scan_fast(
    const void* __restrict__ v, const float* __restrict__ bsum,
    const int* __restrict__ flag, void* __restrict__ out)
{
    if (flag[0]) scanf_body<true>(v, bsum, out);
    else         scanf_body<false>(v, bsum, out);
}

// -------------------------------------------------- K3-slow: ws-less fallback
template <bool F32>
__device__ __forceinline__ void scans_body(const void* v, void* out)
{
    int gid = blockIdx.x;
    int bh = gid & (NBH - 1);
    int ch = gid >> 5;
    int h = bh & 7, b = bh >> 3;
    int t = threadIdx.x;
    int q4 = t & 15, g = t >> 4;

    __shared__ float4 pa[16][16];
    __shared__ float4 gs[16][16];

    float4 ps = {0.f, 0.f, 0.f, 0.f};
    int nprior = ch * CH;
    for (int r = g; r < nprior; r += 16) {
        float4 a = load4<F32>(v, (((size_t)(b * SLK + r)) * NH + h) * DD + q4 * 4);
        ps.x += a.x; ps.y += a.y; ps.z += a.z; ps.w += a.w;
    }
    pa[g][q4] = ps;

    int base_row = ch * CH + g * 8;
    float4 pre[8];
    float4 run = {0.f, 0.f, 0.f, 0.f};
#pragma unroll
    for (int i = 0; i < 8; i++) {
        float4 a = load4<F32>(v, (((size_t)(b * SLK + base_row + i)) * NH + h) * DD + q4 * 4);
        run.x += a.x; run.y += a.y; run.z += a.z; run.w += a.w;
        pre[i] = run;
    }
    gs[g][q4] = run;
    __syncthreads();

    float4 base = {0.f, 0.f, 0.f, 0.f};
#pragma unroll
    for (int g2 = 0; g2 < 16; g2++) {
        float4 a = pa[g2][q4];
        base.x += a.x; base.y += a.y; base.z += a.z; base.w += a.w;
    }
    for (int g2 = 0; g2 < g; g2++) {
        float4 a = gs[g2][q4];
        base.x += a.x; base.y += a.y; base.z += a.z; base.w += a.w;
    }
#pragma unroll
    for (int i = 0; i < 8; i++) {
        float4 o = {base.x + pre[i].x, base.y + pre[i].y,
                    base.z + pre[i].z, base.w + pre[i].w};
        store4<F32>(out, (((size_t)(b * SLQ + base_row + i)) * NH + h) * DD + q4 * 4, o);
    }
}
__global__ __launch_bounds__(256) void k_scan_slow(
    const void* __restrict__ v, const int* __restrict__ flag, void* __restrict__ out)
{
    if (flag[0]) scans_body<true>(v, out);
    else         scans_body<false>(v, out);
}

// -------------------------------------------------- K4: attention rows
// XCD swizzle: bh = gid & 31 -> the 20 blocks per bh share one XCD's L2.
template <bool F32>
__device__ __forceinline__ void attn_body(
    const void* q, const void* k, const void* v,
    const int* topidx, void* out)
{
    int gid = blockIdx.x;
    int bh = gid & (NBH - 1);
    int ug = gid >> 5;                   // 0..19
    int h  = bh & 7, b = bh >> 3;
    int t  = threadIdx.x;
    int lane = t & 63, w = t >> 6;       // 8 waves
    int sl = lane >> 3, c = lane & 7;

    __shared__ float sc[UB][SLK];        // 16 KB
    __shared__ float wred[8][UB];
    __shared__ float gm[UB];
    __shared__ float dinv[UB];
    __shared__ int   lqs[UB];
    __shared__ float part[8][UB][DD];    // 4 KB

    if (t < UB) lqs[t] = topidx[bh * NTOP + ug * UB + t] & (SLQ - 1);
    __syncthreads();

    float q8[UB][8];
#pragma unroll
    for (int j = 0; j < UB; j++)
        load8<F32>(q, (((size_t)(b * SLQ + lqs[j])) * NH + h) * DD + c * 8, q8[j]);

    // phase 1: scores (wave w owns keys [w*256, w*256+256))
#pragma unroll 2
    for (int it = 0; it < 32; it++) {
        int key = w * 256 + it * 8 + sl;
        float k8[8];
        load8<F32>(k, (((size_t)(b * SLK + key)) * NH + h) * DD + c * 8, k8);
#pragma unroll
        for (int j = 0; j < UB; j++) {
            float dot = 0.f;
#pragma unroll
            for (int x = 0; x < 8; x++) dot += q8[j][x] * k8[x];
#pragma unroll
            for (int m = 1; m <= 4; m <<= 1) dot += __shfl_xor(dot, m);
            if (c == j) sc[j][key] = dot * SCL;
        }
    }
    __syncthreads();

    // phase 2: softmax over 2048 per query
#pragma unroll
    for (int j = 0; j < UB; j++) {
        float m = -INFINITY;
#pragma unroll
        for (int i = 0; i < 4; i++) m = fmaxf(m, sc[j][w * 256 + i * 64 + lane]);
#pragma unroll
        for (int mm = 1; mm <= 32; mm <<= 1) m = fmaxf(m, __shfl_xor(m, mm));
        if (lane == 0) wred[w][j] = m;
    }
    __syncthreads();
    if (t < UB) {
        float m = -INFINITY;
#pragma unroll
        for (int w2 = 0; w2 < 8; w2++) m = fmaxf(m, wred[w2][t]);
        gm[t] = m;
    }
    __syncthreads();
#pragma unroll
    for (int j = 0; j < UB; j++) {
        float m = gm[j];
        float s = 0.f;
#pragma unroll
        for (int i = 0; i < 4; i++) {
            int idx = w * 256 + i * 64 + lane;
            float e = expf(sc[j][idx] - m);
            sc[j][idx] = e;
            s += e;
        }
#pragma unroll
        for (int mm = 1; mm <= 32; mm <<= 1) s += __shfl_xor(s, mm);
        if (lane == 0) wred[w][j] = s;
    }
    __syncthreads();
    if (t < UB) {
        float s = 0.f;
#pragma unroll
        for (int w2 = 0; w2 < 8; w2++) s += wred[w2][t];
        dinv[t] = 1.0f / s;
    }
    __syncthreads();

    // phase 3: PV vectorized
    {
        int l16 = lane & 15, r = lane >> 4;
        float4 acc[UB];
#pragma unroll
        for (int j = 0; j < UB; j++) acc[j] = {0.f, 0.f, 0.f, 0.f};
        for (int i = 0; i < 64; i++) {
            int key = w + (i * 4 + r) * 8;
            float4 v4 = load4<F32>(v, (((size_t)(b * SLK + key)) * NH + h) * DD + l16 * 4);
#pragma unroll
            for (int j = 0; j < UB; j++) {
                float sj = sc[j][key];
                acc[j].x += sj * v4.x; acc[j].y += sj * v4.y;
                acc[j].z += sj * v4.z; acc[j].w += sj * v4.w;
            }
        }
#pragma unroll
        for (int j = 0; j < UB; j++) {
#pragma unroll
            for (int mm = 16; mm <= 32; mm <<= 1) {
                acc[j].x += __shfl_xor(acc[j].x, mm);
                acc[j].y += __shfl_xor(acc[j].y, mm);
                acc[j].z += __shfl_xor(acc[j].z, mm);
                acc[j].w += __shfl_xor(acc[j].w, mm);
            }
            if (r == 0) *(float4*)&part[w][j][l16 * 4] = acc[j];
        }
    }
    __syncthreads();
    if (t < UB * DD) {
        int j = t >> 6, d = t & 63;
        float tot = 0.f;
#pragma unroll
        for (int w2 = 0; w2 < 8; w2++) tot += part[w2][j][d];
        se<F32>(out, (((size_t)(b * SLQ + lqs[j])) * NH + h) * DD + d, tot * dinv[j]);
    }
}
__global__ __launch_bounds__(512) void k_attn(
    const void* __restrict__ q, const void* __restrict__ k,
    const void* __restrict__ v, const int* __restrict__ topidx,
    const int* __restrict__ flag, void* __restrict__ out)
{
    if (flag[0]) attn_body<true>(q, k, v, topidx, out);
    else         attn_body<false>(q, k, v, topidx, out);
}

extern "C" void kernel_launch(void* const* d_in, const int* in_sizes, int n_in,
                              void* d_out, int out_size, void* d_ws, size_t ws_size,
                              hipStream_t stream)
{
    const void* q = d_in[0];
    const void* k = d_in[1];
    const void* v = d_in[2];
    const int* isamp = (const int*)d_in[3];

    int* topidx = (int*)d_ws;                    // 5120 B
    int* flag   = (int*)((char*)d_ws + 5120);    // 4 B
    float* bsum = (float*)((char*)d_ws + 8192);  // 128 KB (optional)
    float* M = (float*)d_out;                    // 256 KB scratch, overwritten by scan

    const size_t need = 8192 + (size_t)NBH * NCH * DD * 4;
    const bool fast = ws_size >= need;           // constant across calls -> capture-safe

    k_probe  <<<1,                       64, 0, stream>>>((const unsigned int*)q, flag);
    k_sampleM<<<(NB * NH * SLQ) / 4,    256, 0, stream>>>(q, k, isamp, flag, M);
    k_topk   <<<NBH,                    256, 0, stream>>>(M, topidx);
    if (fast) {
        k_csum     <<<NBH * NCH,        256, 0, stream>>>(v, flag, bsum);
        k_scan_fast<<<NBH * NCH,        256, 0, stream>>>(v, bsum, flag, d_out);
    } else {
        k_scan_slow<<<NBH * NCH,        256, 0, stream>>>(v, flag, d_out);
    }
    k_attn   <<<NBH * NUG,              512, 0, stream>>>(q, k, v, topidx, flag, d_out);
}

// Round 7
// 210.394 us; speedup vs baseline: 3.2349x; 1.3722x over previous
//
#include <hip/hip_runtime.h>
#include <hip/hip_bf16.h>
#include <math.h>

#define NB 4
#define NH 8
#define SLQ 2048
#define SLK 2048
#define DD 64
#define SK 40
#define NTOP 40
#define SCL 0.125f
#define CH 128
#define NCH (SLK / CH) /* 16 */
#define UB 2            /* queries per fallback k_attn block */
#define NUG (NTOP / UB) /* 20 */
#define NBH (NB * NH)   /* 32 */
#define KB 128          /* k_qk key-tile */
#define NKB (SLK / KB)  /* 16 */
#define PVU 4           /* queries per k_pv block */
#define NPG (NTOP / PVU) /* 10 */

typedef unsigned short ushort_t;

__device__ __forceinline__ float bf2f(unsigned int u16) {
    union { unsigned int i; float f; } v;
    v.i = u16 << 16;
    return v.f;
}
__device__ __forceinline__ ushort_t f2bf(float f) {
    union { float f; unsigned int i; } v;
    v.f = f;
    unsigned int x = v.i;
    unsigned int r = (x + 0x7FFFu + ((x >> 16) & 1u)) >> 16;  // RNE
    return (ushort_t)r;
}
template <bool F32>
__device__ __forceinline__ float le(const void* p, size_t i) {
    return F32 ? ((const float*)p)[i] : bf2f(((const ushort_t*)p)[i]);
}
template <bool F32>
__device__ __forceinline__ void se(void* p, size_t i, float v) {
    if (F32) ((float*)p)[i] = v;
    else ((ushort_t*)p)[i] = f2bf(v);
}
template <bool F32>
__device__ __forceinline__ float4 load4(const void* p, size_t off) {
    if (F32) return *(const float4*)((const float*)p + off);
    uint2 u = *(const uint2*)((const ushort_t*)p + off);
    float4 r;
    r.x = bf2f(u.x & 0xffffu); r.y = bf2f(u.x >> 16);
    r.z = bf2f(u.y & 0xffffu); r.w = bf2f(u.y >> 16);
    return r;
}
template <bool F32>
__device__ __forceinline__ void store4(void* p, size_t off, float4 v) {
    if (F32) { *(float4*)((float*)p + off) = v; return; }
    uint2 u;
    u.x = (unsigned)f2bf(v.x) | ((unsigned)f2bf(v.y) << 16);
    u.y = (unsigned)f2bf(v.z) | ((unsigned)f2bf(v.w) << 16);
    *(uint2*)((ushort_t*)p + off) = u;
}
template <bool F32>
__device__ __forceinline__ void load8(const void* p, size_t elem_off, float* r) {
    if (F32) {
        const float4* q = (const float4*)((const float*)p + elem_off);
        float4 a = q[0], b = q[1];
        r[0] = a.x; r[1] = a.y; r[2] = a.z; r[3] = a.w;
        r[4] = b.x; r[5] = b.y; r[6] = b.z; r[7] = b.w;
    } else {
        uint4 u = *(const uint4*)((const ushort_t*)p + elem_off);
        unsigned int w[4] = {u.x, u.y, u.z, u.w};
#pragma unroll
        for (int j = 0; j < 4; j++) {
            r[2 * j + 0] = bf2f(w[j] & 0xffffu);
            r[2 * j + 1] = bf2f(w[j] >> 16);
        }
    }
}

// -------------------------------------------------- K0: dtype probe
__global__ void k_probe(const unsigned int* __restrict__ qw, int* __restrict__ flag)
{
    int t = threadIdx.x;  // 64 threads
    unsigned int w = qw[t * 37];
    int cnt = 0;
#pragma unroll
    for (int s = 0; s < 2; s++) {
        unsigned int h = (s == 0) ? (w & 0xffffu) : (w >> 16);
        unsigned int e = (h >> 7) & 0xffu;
        int ok = (e == 0) ? ((h & 0x7fu) == 0) : (e >= 100 && e <= 153);
        cnt += ok;
    }
#pragma unroll
    for (int off = 32; off > 0; off >>= 1) cnt += __shfl_xor(cnt, off);
    if (t == 0) flag[0] = (cnt >= 104) ? 0 : 1;
}

// -------------------------------------------------- K1: sampled M (wave per query)
template <bool F32>
__device__ __forceinline__ void sampleM_body(
    const void* q, const void* k, const int* isamp, float* M)
{
    int t = threadIdx.x;
    int lane = t & 63;
    int blk = blockIdx.x;
    int bh = blk & (NBH - 1);
    int lgrp = blk >> 5;
    int l = lgrp * 4 + (t >> 6);
    int h  = bh & (NH - 1);
    int b  = bh >> 3;
    int sl = lane >> 3, c = lane & 7;

    float q8[8];
    load8<F32>(q, (((size_t)(b * SLQ + l)) * NH + h) * DD + c * 8, q8);
    int il = (lane < SK) ? (isamp[l * SK + lane] & (SLK - 1)) : 0;

    float mx = -INFINITY, sm = 0.f;
#pragma unroll
    for (int it = 0; it < SK / 8; it++) {
        int s = it * 8 + sl;
        int ks = __shfl(il, s);
        float k8[8];
        load8<F32>(k, (((size_t)(b * SLK + ks)) * NH + h) * DD + c * 8, k8);
        float dot = 0.f;
#pragma unroll
        for (int j = 0; j < 8; j++) dot += q8[j] * k8[j];
#pragma unroll
        for (int m = 1; m <= 4; m <<= 1) dot += __shfl_xor(dot, m);
        mx = fmaxf(mx, dot);
        sm += dot;
    }
#pragma unroll
    for (int m = 8; m <= 32; m <<= 1) {
        mx = fmaxf(mx, __shfl_xor(mx, m));
        sm += __shfl_xor(sm, m);
    }
    if (lane == 0) M[(size_t)bh * SLQ + l] = mx - sm * (1.0f / SK);
}
__global__ __launch_bounds__(256) void k_sampleM(
    const void* __restrict__ q, const void* __restrict__ k,
    const int* __restrict__ isamp, const int* __restrict__ flag,
    float* __restrict__ M)
{
    if (flag[0]) sampleM_body<true>(q, k, isamp, M);
    else         sampleM_body<false>(q, k, isamp, M);
}

// -------------------------------------------------- K2: top-40 (NaN-proof)
__global__ __launch_bounds__(256) void k_topk(
    const float* __restrict__ M, int* __restrict__ topidx)
{
    int bh = blockIdx.x;
    int t = threadIdx.x;
    int lane = t & 63, wid = t >> 6;
    __shared__ float vals[SLQ];
    __shared__ float wbv[4];
    __shared__ int   wbi[4];
    const float* Mp = M + (size_t)bh * SLQ;
    for (int i = t; i < SLQ; i += 256) vals[i] = Mp[i];
    __syncthreads();
    for (int u = 0; u < NTOP; u++) {
        float bv = -INFINITY; int bi = t;
        for (int i = t; i < SLQ; i += 256) {
            float v = vals[i];
            if (v > bv) { bv = v; bi = i; }
        }
#pragma unroll
        for (int off = 32; off > 0; off >>= 1) {
            float ov = __shfl_xor(bv, off);
            int   oi = __shfl_xor(bi, off);
            if (ov > bv || (ov == bv && oi < bi)) { bv = ov; bi = oi; }
        }
        if (lane == 0) { wbv[wid] = bv; wbi[wid] = bi; }
        __syncthreads();
        if (t == 0) {
            float fv = wbv[0]; int fi = wbi[0];
#pragma unroll
            for (int w = 1; w < 4; w++) {
                if (wbv[w] > fv || (wbv[w] == fv && wbi[w] < fi)) { fv = wbv[w]; fi = wbi[w]; }
            }
            fi &= (SLQ - 1);
            topidx[bh * NTOP + u] = fi;
            vals[fi] = -INFINITY;
        }
        __syncthreads();
    }
}

// -------------------------------------------------- K5a: QK^T scores (two-stage path)
// grid = (bh low 5 bits, kb). LDS-staged K-tile (transposed) + 40 Q rows.
// Each thread computes a 5u x 4key register tile. S written to d_out scratch.
template <bool F32>
__device__ __forceinline__ void qk_body(
    const void* q, const void* k, const int* topidx, void* S)
{
    int gid = blockIdx.x;
    int bh = gid & (NBH - 1);
    int kb = gid >> 5;
    int h = bh & 7, b = bh >> 3;
    int t = threadIdx.x;

    __shared__ float Ktd[DD][KB + 4];   // transposed, padded: 33 KB
    __shared__ float Qs[NTOP][DD + 4];  // 10.6 KB
    __shared__ int lqs[NTOP];

    if (t < NTOP) lqs[t] = topidx[bh * NTOP + t] & (SLQ - 1);
    __syncthreads();

    // stage K tile transposed: 2 threads per row, 32 floats each
    {
        int r = t >> 1, half = t & 1;
        int key = kb * KB + r;
        size_t base = (((size_t)(b * SLK + key)) * NH + h) * DD + half * 32;
#pragma unroll
        for (int i = 0; i < 8; i++) {
            float4 a = load4<F32>(k, base + i * 4);
            int d0 = half * 32 + i * 4;
            Ktd[d0 + 0][r] = a.x; Ktd[d0 + 1][r] = a.y;
            Ktd[d0 + 2][r] = a.z; Ktd[d0 + 3][r] = a.w;
        }
    }
    // stage Q rows (40 x 64)
    for (int lin = t; lin < NTOP * DD / 4; lin += 256) {
        int u = (lin * 4) >> 6, d0 = (lin * 4) & 63;
        float4 a = load4<F32>(q, (((size_t)(b * SLQ + lqs[u])) * NH + h) * DD + d0);
        Qs[u][d0 + 0] = a.x; Qs[u][d0 + 1] = a.y;
        Qs[u][d0 + 2] = a.z; Qs[u][d0 + 3] = a.w;
    }
    __syncthreads();

    int ug = t >> 5;      // 0..7 -> 5 u's each
    int kg = t & 31;      // 0..31 -> 4 keys each
    float4 acc[5];
#pragma unroll
    for (int u = 0; u < 5; u++) acc[u] = {0.f, 0.f, 0.f, 0.f};

#pragma unroll 4
    for (int d4 = 0; d4 < 16; d4++) {
        float4 q4[5];
#pragma unroll
        for (int u = 0; u < 5; u++)
            q4[u] = *(const float4*)&Qs[ug * 5 + u][d4 * 4];
#pragma unroll
        for (int j = 0; j < 4; j++) {
            float4 k4 = *(const float4*)&Ktd[d4 * 4 + j][kg * 4];
            float qs;
#pragma unroll
            for (int u = 0; u < 5; u++) {
                qs = (j == 0) ? q4[u].x : (j == 1) ? q4[u].y : (j == 2) ? q4[u].z : q4[u].w;
                acc[u].x += qs * k4.x; acc[u].y += qs * k4.y;
                acc[u].z += qs * k4.z; acc[u].w += qs * k4.w;
            }
        }
    }
#pragma unroll
    for (int u = 0; u < 5; u++) {
        float4 s4 = {acc[u].x * SCL, acc[u].y * SCL, acc[u].z * SCL, acc[u].w * SCL};
        store4<F32>(S, ((size_t)(bh * NTOP + ug * 5 + u)) * SLK + kb * KB + kg * 4, s4);
    }
}
__global__ __launch_bounds__(256) void k_qk(
    const void* __restrict__ q, const void* __restrict__ k,
    const int* __restrict__ topidx, const int* __restrict__ flag,
    void* __restrict__ S)
{
    if (flag[0]) qk_body<true>(q, k, topidx, S);
    else         qk_body<false>(q, k, topidx, S);
}

// -------------------------------------------------- K5b: softmax + PV -> ctxv
// grid = (bh low 5 bits, ug of PVU=4 queries) = 320 blocks x 256 threads.
template <bool F32>
__device__ __forceinline__ void pv_body(
    const void* S, const void* v, float* ctxv)
{
    int gid = blockIdx.x;
    int bh = gid & (NBH - 1);
    int ug = gid >> 5;                 // 0..9
    int h = bh & 7, b = bh >> 3;
    int t = threadIdx.x;
    int lane = t & 63, w = t >> 6;     // 4 waves

    __shared__ float sc[PVU][SLK];     // 32 KB
    __shared__ float4 part[16][PVU][16]; // 16 KB
    __shared__ float dinv[PVU];

    // load scores: 4 rows x 2048, coalesced float4
    for (int i = 0; i < 8; i++) {
        int lin = (i * 256 + t) * 4;
        int j = lin >> 11, key = lin & (SLK - 1);
        float4 a = load4<F32>(S, ((size_t)(bh * NTOP + ug * PVU + j)) * SLK + key);
        *(float4*)&sc[j][key] = a;
    }
    __syncthreads();

    // softmax: wave w owns row w
    {
        int j = w;
        float m = -INFINITY;
#pragma unroll
        for (int i = 0; i < 32; i++) m = fmaxf(m, sc[j][i * 64 + lane]);
#pragma unroll
        for (int mm = 1; mm <= 32; mm <<= 1) m = fmaxf(m, __shfl_xor(m, mm));
        float s = 0.f;
#pragma unroll
        for (int i = 0; i < 32; i++) {
            float e = expf(sc[j][i * 64 + lane] - m);
            sc[j][i * 64 + lane] = e;
            s += e;
        }
#pragma unroll
        for (int mm = 1; mm <= 32; mm <<= 1) s += __shfl_xor(s, mm);
        if (lane == 0) dinv[j] = 1.0f / s;
    }
    __syncthreads();

    // PV: thread = (rg = t>>4 key phase, d4 = t&15 col), fully coalesced V
    {
        int d4 = t & 15, rg = t >> 4;
        float4 acc[PVU];
#pragma unroll
        for (int j = 0; j < PVU; j++) acc[j] = {0.f, 0.f, 0.f, 0.f};
        for (int i = 0; i < SLK / 16; i++) {
            int key = rg + i * 16;
            float4 v4 = load4<F32>(v, (((size_t)(b * SLK + key)) * NH + h) * DD + d4 * 4);
#pragma unroll
            for (int j = 0; j < PVU; j++) {
                float sj = sc[j][key];
                acc[j].x += sj * v4.x; acc[j].y += sj * v4.y;
                acc[j].z += sj * v4.z; acc[j].w += sj * v4.w;
            }
        }
#pragma unroll
        for (int j = 0; j < PVU; j++) part[rg][j][d4] = acc[j];
    }
    __syncthreads();
    if (t < 64) {
        int j = t >> 4, d4 = t & 15;
        float4 tot = part[0][j][d4];
#pragma unroll
        for (int rg = 1; rg < 16; rg++) {
            float4 a = part[rg][j][d4];
            tot.x += a.x; tot.y += a.y; tot.z += a.z; tot.w += a.w;
        }
        float di = dinv[j];
        tot.x *= di; tot.y *= di; tot.z *= di; tot.w *= di;
        *(float4*)&ctxv[((size_t)(bh * NTOP + ug * PVU + j)) * DD + d4 * 4] = tot;
    }
}
__global__ __launch_bounds__(256) void k_pv(
    const void* __restrict__ S, const void* __restrict__ v,
    const int* __restrict__ flag, float* __restrict__ ctxv)
{
    if (flag[0]) pv_body<true>(S, v, ctxv);
    else         pv_body<false>(S, v, ctxv);
}

// -------------------------------------------------- K5c: scatter ctxv rows into out
template <bool F32>
__device__ __forceinline__ void scatter_body(
    const float* ctxv, const int* topidx, void* out)
{
    int gid = blockIdx.x;
    int bh = gid & (NBH - 1);
    int ug = gid >> 5;
    int h = bh & 7, b = bh >> 3;
    int t = threadIdx.x;
    int j = t >> 6, d = t & 63;
    int u = ug * PVU + j;
    int lq = topidx[bh * NTOP + u] & (SLQ - 1);
    se<F32>(out, (((size_t)(b * SLQ + lq)) * NH + h) * DD + d,
            ctxv[((size_t)(bh * NTOP + u)) * DD + d]);
}
__global__ __launch_bounds__(256) void k_scatter(
    const float* __restrict__ ctxv, const int* __restrict__ topidx,
    const int* __restrict__ flag, void* __restrict__ out)
{
    if (flag[0]) scatter_body<true>(ctxv, topidx, out);
    else         scatter_body<false>(ctxv, topidx, out);
}

// -------------------------------------------------- K3a: per-chunk column sums
template <bool F32>
__device__ __forceinline__ void csum_body(const void* v, float* bsum)
{
    int gid = blockIdx.x;
    int bh = gid & (NBH - 1);
    int ch = gid >> 5;
    int h = bh & 7, b = bh >> 3;
    int t = threadIdx.x;
    int q4 = t & 15, g = t >> 4;
    int base_row = ch * CH + g * 8;

    float4 s = {0.f, 0.f, 0.f, 0.f};
#pragma unroll
    for (int i = 0; i < 8; i++) {
        float4 a = load4<F32>(v, (((size_t)(b * SLK + base_row + i)) * NH + h) * DD + q4 * 4);
        s.x += a.x; s.y += a.y; s.z += a.z; s.w += a.w;
    }
    __shared__ float4 gs[16][16];
    gs[g][q4] = s;
    __syncthreads();
    if (t < 16) {
        float4 tot = gs[0][t];
#pragma unroll
        for (int g2 = 1; g2 < 16; g2++) {
            tot.x += gs[g2][t].x; tot.y += gs[g2][t].y;
            tot.z += gs[g2][t].z; tot.w += gs[g2][t].w;
        }
        *(float4*)&bsum[((size_t)bh * NCH + ch) * DD + t * 4] = tot;
    }
}
__global__ __launch_bounds__(256) void k_csum(
    const void* __restrict__ v, const int* __restrict__ flag, float* __restrict__ bsum)
{
    if (flag[0]) csum_body<true>(v, bsum);
    else         csum_body<false>(v, bsum);
}

// -------------------------------------------------- K3b: scan using chunk sums
template <bool F32>
__device__ __forceinline__ void scanf_body(const void* v, const float* bsum, void* out)
{
    int gid = blockIdx.x;
    int bh = gid & (NBH - 1);
    int ch = gid >> 5;
    int h = bh & 7, b = bh >> 3;
    int t = threadIdx.x;
    int q4 = t & 15, g = t >> 4;
    int base_row = ch * CH + g * 8;

    float4 pre[8];
    float4 run = {0.f, 0.f, 0.f, 0.f};
#pragma unroll
    for (int i = 0; i < 8; i++) {
        float4 a = load4<F32>(v, (((size_t)(b * SLK + base_row + i)) * NH + h) * DD + q4 * 4);
        run.x += a.x; run.y += a.y; run.z += a.z; run.w += a.w;
        pre[i] = run;
    }
    __shared__ float4 gs[16][16];
    gs[g][q4] = run;
    __syncthreads();

    float4 base = {0.f, 0.f, 0.f, 0.f};
    for (int c = 0; c < ch; c++) {
        float4 a = *(const float4*)&bsum[((size_t)bh * NCH + c) * DD + q4 * 4];
        base.x += a.x; base.y += a.y; base.z += a.z; base.w += a.w;
    }
    for (int g2 = 0; g2 < g; g2++) {
        float4 a = gs[g2][q4];
        base.x += a.x; base.y += a.y; base.z += a.z; base.w += a.w;
    }
#pragma unroll
    for (int i = 0; i < 8; i++) {
        float4 o = {base.x + pre[i].x, base.y + pre[i].y,
                    base.z + pre[i].z, base.w + pre[i].w};
        store4<F32>(out, (((size_t)(b * SLQ + base_row + i)) * NH + h) * DD + q4 * 4, o);
    }
}
__global__ __launch_bounds__(256) void k_scan_fast(
    const void* __restrict__ v, const float* __restrict__ bsum,
    const int* __restrict__ flag, void* __restrict__ out)
{
    if (flag[0]) scanf_body<true>(v, bsum, out);
    else         scanf_body<false>(v, bsum, out);
}

// -------------------------------------------------- K3-slow: ws-less fallback
template <bool F32>
__device__ __forceinline__ void scans_body(const void* v, void* out)
{
    int gid = blockIdx.x;
    int bh = gid & (NBH - 1);
    int ch = gid >> 5;
    int h = bh & 7, b = bh >> 3;
    int t = threadIdx.x;
    int q4 = t & 15, g = t >> 4;

    __shared__ float4 pa[16][16];
    __shared__ float4 gs[16][16];

    float4 ps = {0.f, 0.f, 0.f, 0.f};
    int nprior = ch * CH;
    for (int r = g; r < nprior; r += 16) {
        float4 a = load4<F32>(v, (((size_t)(b * SLK + r)) * NH + h) * DD + q4 * 4);
        ps.x += a.x; ps.y += a.y; ps.z += a.z; ps.w += a.w;
    }
    pa[g][q4] = ps;

    int base_row = ch * CH + g * 8;
    float4 pre[8];
    float4 run = {0.f, 0.f, 0.f, 0.f};
#pragma unroll
    for (int i = 0; i < 8; i++) {
        float4 a = load4<F32>(v, (((size_t)(b * SLK + base_row + i)) * NH + h) * DD + q4 * 4);
        run.x += a.x; run.y += a.y; run.z += a.z; run.w += a.w;
        pre[i] = run;
    }
    gs[g][q4] = run;
    __syncthreads();

    float4 base = {0.f, 0.f, 0.f, 0.f};
#pragma unroll
    for (int g2 = 0; g2 < 16; g2++) {
        float4 a = pa[g2][q4];
        base.x += a.x; base.y += a.y; base.z += a.z; base.w += a.w;
    }
    for (int g2 = 0; g2 < g; g2++) {
        float4 a = gs[g2][q4];
        base.x += a.x; base.y += a.y; base.z += a.z; base.w += a.w;
    }
#pragma unroll
    for (int i = 0; i < 8; i++) {
        float4 o = {base.x + pre[i].x, base.y + pre[i].y,
                    base.z + pre[i].z, base.w + pre[i].w};
        store4<F32>(out, (((size_t)(b * SLQ + base_row + i)) * NH + h) * DD + q4 * 4, o);
    }
}
__global__ __launch_bounds__(256) void k_scan_slow(
    const void* __restrict__ v, const int* __restrict__ flag, void* __restrict__ out)
{
    if (flag[0]) scans_body<true>(v, out);
    else         scans_body<false>(v, out);
}

// -------------------------------------------------- K4: fused attention (fallback)
template <bool F32>
__device__ __forceinline__ void attn_body(
    const void* q, const void* k, const void* v,
    const int* topidx, void* out)
{
    int gid = blockIdx.x;
    int bh = gid & (NBH - 1);
    int ug = gid >> 5;
    int h  = bh & 7, b = bh >> 3;
    int t  = threadIdx.x;
    int lane = t & 63, w = t >> 6;
    int sl = lane >> 3, c = lane & 7;

    __shared__ float sc[UB][SLK];
    __shared__ float wred[8][UB];
    __shared__ float gm[UB];
    __shared__ float dinv[UB];
    __shared__ int   lqs[UB];
    __shared__ float part[8][UB][DD];

    if (t < UB) lqs[t] = topidx[bh * NTOP + ug * UB + t] & (SLQ - 1);
    __syncthreads();

    float q8[UB][8];
#pragma unroll
    for (int j = 0; j < UB; j++)
        load8<F32>(q, (((size_t)(b * SLQ + lqs[j])) * NH + h) * DD + c * 8, q8[j]);

#pragma unroll 2
    for (int it = 0; it < 32; it++) {
        int key = w * 256 + it * 8 + sl;
        float k8[8];
        load8<F32>(k, (((size_t)(b * SLK + key)) * NH + h) * DD + c * 8, k8);
#pragma unroll
        for (int j = 0; j < UB; j++) {
            float dot = 0.f;
#pragma unroll
            for (int x = 0; x < 8; x++) dot += q8[j][x] * k8[x];
#pragma unroll
            for (int m = 1; m <= 4; m <<= 1) dot += __shfl_xor(dot, m);
            if (c == j) sc[j][key] = dot * SCL;
        }
    }
    __syncthreads();

#pragma unroll
    for (int j = 0; j < UB; j++) {
        float m = -INFINITY;
#pragma unroll
        for (int i = 0; i < 4; i++) m = fmaxf(m, sc[j][w * 256 + i * 64 + lane]);
#pragma unroll
        for (int mm = 1; mm <= 32; mm <<= 1) m = fmaxf(m, __shfl_xor(m, mm));
        if (lane == 0) wred[w][j] = m;
    }
    __syncthreads();
    if (t < UB) {
        float m = -INFINITY;
#pragma unroll
        for (int w2 = 0; w2 < 8; w2++) m = fmaxf(m, wred[w2][t]);
        gm[t] = m;
    }
    __syncthreads();
#pragma unroll
    for (int j = 0; j < UB; j++) {
        float m = gm[j];
        float s = 0.f;
#pragma unroll
        for (int i = 0; i < 4; i++) {
            int idx = w * 256 + i * 64 + lane;
            float e = expf(sc[j][idx] - m);
            sc[j][idx] = e;
            s += e;
        }
#pragma unroll
        for (int mm = 1; mm <= 32; mm <<= 1) s += __shfl_xor(s, mm);
        if (lane == 0) wred[w][j] = s;
    }
    __syncthreads();
    if (t < UB) {
        float s = 0.f;
#pragma unroll
        for (int w2 = 0; w2 < 8; w2++) s += wred[w2][t];
        dinv[t] = 1.0f / s;
    }
    __syncthreads();

    {
        int l16 = lane & 15, r = lane >> 4;
        float4 acc[UB];
#pragma unroll
        for (int j = 0; j < UB; j++) acc[j] = {0.f, 0.f, 0.f, 0.f};
        for (int i = 0; i < 64; i++) {
            int key = w + (i * 4 + r) * 8;
            float4 v4 = load4<F32>(v, (((size_t)(b * SLK + key)) * NH + h) * DD + l16 * 4);
#pragma unroll
            for (int j = 0; j < UB; j++) {
                float sj = sc[j][key];
                acc[j].x += sj * v4.x; acc[j].y += sj * v4.y;
                acc[j].z += sj * v4.z; acc[j].w += sj * v4.w;
            }
        }
#pragma unroll
        for (int j = 0; j < UB; j++) {
#pragma unroll
            for (int mm = 16; mm <= 32; mm <<= 1) {
                acc[j].x += __shfl_xor(acc[j].x, mm);
                acc[j].y += __shfl_xor(acc[j].y, mm);
                acc[j].z += __shfl_xor(acc[j].z, mm);
                acc[j].w += __shfl_xor(acc[j].w, mm);
            }
            if (r == 0) *(float4*)&part[w][j][l16 * 4] = acc[j];
        }
    }
    __syncthreads();
    if (t < UB * DD) {
        int j = t >> 6, d = t & 63;
        float tot = 0.f;
#pragma unroll
        for (int w2 = 0; w2 < 8; w2++) tot += part[w2][j][d];
        se<F32>(out, (((size_t)(b * SLQ + lqs[j])) * NH + h) * DD + d, tot * dinv[j]);
    }
}
__global__ __launch_bounds__(512) void k_attn(
    const void* __restrict__ q, const void* __restrict__ k,
    const void* __restrict__ v, const int* __restrict__ topidx,
    const int* __restrict__ flag, void* __restrict__ out)
{
    if (flag[0]) attn_body<true>(q, k, v, topidx, out);
    else         attn_body<false>(q, k, v, topidx, out);
}

extern "C" void kernel_launch(void* const* d_in, const int* in_sizes, int n_in,
                              void* d_out, int out_size, void* d_ws, size_t ws_size,
                              hipStream_t stream)
{
    const void* q = d_in[0];
    const void* k = d_in[1];
    const void* v = d_in[2];
    const int* isamp = (const int*)d_in[3];

    // ws layout: topidx 5120 | flag 4 | (pad to 8192) | bsum 128K | ctxv 320K
    int* topidx = (int*)d_ws;
    int* flag   = (int*)((char*)d_ws + 5120);
    float* bsum = (float*)((char*)d_ws + 8192);
    float* ctxv = (float*)((char*)d_ws + 8192 + 131072);
    // M (256 KB fp32) and S (scores) both live in d_out scratch; M consumed by
    // topk before k_qk overwrites; S consumed by k_pv before scan overwrites.
    float* M = (float*)d_out;
    void* S  = d_out;

    const size_t need_fast = 8192 + (size_t)NBH * NCH * DD * 4;              // 139 KB
    const size_t need_two  = need_fast + (size_t)NBH * NTOP * DD * 4;        // 467 KB
    const bool fast = ws_size >= need_fast;
    const bool two  = ws_size >= need_two;

    k_probe  <<<1,                       64, 0, stream>>>((const unsigned int*)q, flag);
    k_sampleM<<<(NB * NH * SLQ) / 4,    256, 0, stream>>>(q, k, isamp, flag, M);
    k_topk   <<<NBH,                    256, 0, stream>>>(M, topidx);

    if (two) {
        k_qk   <<<NBH * NKB,            256, 0, stream>>>(q, k, topidx, flag, S);
        k_pv   <<<NBH * NPG,            256, 0, stream>>>(S, v, flag, ctxv);
        k_csum     <<<NBH * NCH,        256, 0, stream>>>(v, flag, bsum);
        k_scan_fast<<<NBH * NCH,        256, 0, stream>>>(v, bsum, flag, d_out);
        k_scatter  <<<NBH * NPG,        256, 0, stream>>>(ctxv, topidx, flag, d_out);
    } else {
        if (fast) {
            k_csum     <<<NBH * NCH,    256, 0, stream>>>(v, flag, bsum);
            k_scan_fast<<<NBH * NCH,    256, 0, stream>>>(v, bsum, flag, d_out);
        } else {
            k_scan_slow<<<NBH * NCH,    256, 0, stream>>>(v, flag, d_out);
        }
        k_attn <<<NBH * NUG,            512, 0, stream>>>(q, k, v, topidx, flag, d_out);
    }
}